// Round 2
// 483.966 us; speedup vs baseline: 1.0057x; 1.0057x over previous
//
#include <hip/hip_runtime.h>
#include <hip/hip_bf16.h>
#include <cstdint>

using u16 = unsigned short;
using u32 = unsigned int;

typedef __bf16 bf16x8 __attribute__((ext_vector_type(8)));
typedef float  f32x4  __attribute__((ext_vector_type(4)));

#define DEV static __device__ __forceinline__

DEV float bf2f(u16 u){ union { u32 u; float f; } c; c.u = ((u32)u) << 16; return c.f; }

// hardware RNE f32->bf16
DEV u16 f2bf(float f){
  __bf16 h = (__bf16)f;
  return __builtin_bit_cast(u16, h);
}

DEV float fast_rcp(float x){ return __builtin_amdgcn_rcpf(x); }

DEV void async16(const u16* g, u16* l){
  __builtin_amdgcn_global_load_lds((const __attribute__((address_space(1))) u32*)g,
                                   (__attribute__((address_space(3))) u32*)l,
                                   16, 0, 0);
}

#define BARRIER() __builtin_amdgcn_s_barrier()
#define LGKM0() do { __asm__ volatile("s_waitcnt lgkmcnt(0)" ::: "memory"); \
                     __builtin_amdgcn_sched_barrier(0); } while (0)
#define VMCNT(n) __asm__ volatile("s_waitcnt vmcnt(" #n ")" ::: "memory")

// ---------------- fused weight transposes + f32->bf16 (one launch) ----------------
__global__ __launch_bounds__(256)
void transpose_all(const float* __restrict__ W0, const float* __restrict__ W1,
                   const float* __restrict__ W2, const float* __restrict__ W3,
                   const float* __restrict__ W4, const float* __restrict__ W5,
                   u16* __restrict__ T0, u16* __restrict__ T1, u16* __restrict__ T2,
                   u16* __restrict__ T3, u16* __restrict__ T4, u16* __restrict__ T5){
  const int z = blockIdx.z;
  const float* W; u16* WT; int R, C;
  switch (z){
    case 0:  W = W0; WT = T0; R = 512;  C = 1024; break;
    case 1:  W = W1; WT = T1; R = 512;  C = 1024; break;
    case 2:  W = W2; WT = T2; R = 512;  C = 1024; break;
    case 3:  W = W3; WT = T3; R = 1024; C = 512;  break;
    case 4:  W = W4; WT = T4; R = 512;  C = 1024; break;
    default: W = W5; WT = T5; R = 1024; C = 512;  break;
  }
  const int c0 = blockIdx.x * 32, r0 = blockIdx.y * 32;
  if (c0 >= C || r0 >= R) return;
  __shared__ float tile[32][33];
  const int tx = threadIdx.x, ty = threadIdx.y;  // (32,8)
  #pragma unroll
  for (int j = 0; j < 4; ++j)
    tile[ty + j*8][tx] = W[(size_t)(r0 + ty + j*8) * C + (c0 + tx)];
  __syncthreads();
  #pragma unroll
  for (int j = 0; j < 4; ++j)
    WT[(size_t)(c0 + ty + j*8) * R + (r0 + tx)] = f2bf(tile[tx][ty + j*8]);
}

// ---------------- LayerNorm: one wave per 512-elem row ----------------
template<bool BF16IN>
__global__ __launch_bounds__(256)
void ln_kernel(const void* __restrict__ xin, const float* __restrict__ gamma,
               const float* __restrict__ beta, u16* __restrict__ xout){
  const int wid = threadIdx.x >> 6;
  const int lane = threadIdx.x & 63;
  const size_t row = (size_t)blockIdx.x * 4 + wid;
  const int d0 = lane * 8;
  float v[8];
  if constexpr (BF16IN){
    const u16* xp = (const u16*)xin + row * 512 + d0;
    uint4 p = *(const uint4*)xp;
    const u16* s = (const u16*)&p;
    #pragma unroll
    for (int i = 0; i < 8; ++i) v[i] = bf2f(s[i]);
  } else {
    const float* xp = (const float*)xin + row * 512 + d0;
    float4 p0 = *(const float4*)xp;
    float4 p1 = *(const float4*)(xp + 4);
    v[0]=p0.x; v[1]=p0.y; v[2]=p0.z; v[3]=p0.w;
    v[4]=p1.x; v[5]=p1.y; v[6]=p1.z; v[7]=p1.w;
  }
  float s = 0.f, sq = 0.f;
  #pragma unroll
  for (int i = 0; i < 8; ++i){ s += v[i]; sq += v[i]*v[i]; }
  #pragma unroll
  for (int o = 32; o >= 1; o >>= 1){ s += __shfl_xor(s, o); sq += __shfl_xor(sq, o); }
  const float mu  = s * (1.0f/512.0f);
  const float var = sq * (1.0f/512.0f) - mu*mu;
  const float rstd = rsqrtf(var + 1e-5f);
  const float4 g0 = *(const float4*)(gamma + d0);
  const float4 g1 = *(const float4*)(gamma + d0 + 4);
  const float4 b0 = *(const float4*)(beta + d0);
  const float4 b1 = *(const float4*)(beta + d0 + 4);
  float gg[8] = {g0.x,g0.y,g0.z,g0.w,g1.x,g1.y,g1.z,g1.w};
  float bb[8] = {b0.x,b0.y,b0.z,b0.w,b1.x,b1.y,b1.z,b1.w};
  u16 o8[8];
  #pragma unroll
  for (int i = 0; i < 8; ++i)
    o8[i] = f2bf((v[i]-mu)*rstd*gg[i] + bb[i]);
  *(uint4*)(xout + row*512 + d0) = *(const uint4*)o8;
}

// ---- fused AFT: weighted[t,h] = sum_b n*v / sum_b n ; Yt[b,t,h] = Qsig[b,t,h]*weighted ----
__global__ __launch_bounds__(256)
void aft_fused(const u16* __restrict__ numer, const u16* __restrict__ V,
               const u16* __restrict__ qs, u16* __restrict__ yt){
  const size_t TH = (size_t)4096 * 1024;
  const size_t i8 = ((size_t)blockIdx.x * 256 + threadIdx.x) * 8;
  float den[8], ws[8];
  #pragma unroll
  for (int j = 0; j < 8; ++j){ den[j] = 0.f; ws[j] = 0.f; }
  #pragma unroll
  for (int b = 0; b < 8; ++b){
    uint4 pn = *(const uint4*)(numer + b*TH + i8);
    uint4 pv = *(const uint4*)(V     + b*TH + i8);
    const u16* n = (const u16*)&pn;
    const u16* v = (const u16*)&pv;
    #pragma unroll
    for (int j = 0; j < 8; ++j){ float nf = bf2f(n[j]); den[j] += nf; ws[j] += nf * bf2f(v[j]); }
  }
  float w[8];
  #pragma unroll
  for (int j = 0; j < 8; ++j) w[j] = ws[j] * fast_rcp(den[j]);
  #pragma unroll
  for (int b = 0; b < 8; ++b){
    uint4 pq = *(const uint4*)(qs + b*TH + i8);
    const u16* q = (const u16*)&pq;
    u16 o[8];
    #pragma unroll
    for (int j = 0; j < 8; ++j) o[j] = f2bf(bf2f(q[j]) * w[j]);
    *(uint4*)(yt + b*TH + i8) = *(const uint4*)o;
  }
}

// ========= 256x256 bf16 MFMA GEMM, C = A[M,K] @ Bt[N,K]^T — 8-phase, 64KB static LDS =========
// 8 waves (2M x 4N), per-wave 128x64 output, BK=64, SINGLE 64 KiB buffer (capture-safe:
// no dynamic LDS, no hipFuncSetAttribute). Quadrant rotation with register-held B0/B1 so
// every LDS half is ds_read exactly once per tile and its slot is immediately re-staged
// for tile t+1:
//   q0: ds_read A0,B0 -> MF(0,0)                    | end: vmcnt(2)  (B1(t) landed)
//   q1: ds_read B1 ; stage (t+1).A0,B0 -> MF(0,1)   | end: vmcnt(4)  (A1(t) landed)
//   q2: ds_read A1 ; stage (t+1).B1   -> MF(1,1)    | end: barrier only
//   q3: stage (t+1).A1 ; MF(1,0) [regs only]        | end: vmcnt(4)  (A0,B0(t+1) landed)
// Counted vmcnt keeps 2-4 half-tiles in flight across barriers (never drains to 0 in the
// main loop). lgkmcnt(0)+sched_barrier before each MFMA cluster; setprio(1) around MFMA.
// XOR swizzle (chunk ^= row&7) on pre-swizzled GLOBAL source + swizzled ds_read address;
// LDS writes stay linear (global_load_lds requirement).
template<int EPI, int KC>
__global__ __launch_bounds__(512, 2)
void gemm256(const u16* __restrict__ A, const u16* __restrict__ Bt,
             const float* __restrict__ bias0, const float* __restrict__ wbias,
             u16* __restrict__ out0, u16* __restrict__ out1, u16* __restrict__ out2,
             const float* __restrict__ bias1, const float* __restrict__ bias2,
             const u16* __restrict__ resid, float* __restrict__ outf){
  constexpr int NK = KC / 64;
  __shared__ __align__(16) char smem[65536];  // A0|A1|B0|B1, 16 KiB each

  const int tid  = threadIdx.x;
  const int wid  = tid >> 6;
  const int lane = tid & 63;
  const int quad = lane >> 4;
  const int lr   = lane & 15;
  const int wm   = wid & 1;      // M-wave (2)
  const int wn   = wid >> 1;     // N-wave (4)

  // bijective XCD swizzle (all grids are multiples of 8); M fastest (128 M-tiles).
  const int nwg = gridDim.x;
  const int wg  = (blockIdx.x & 7) * (nwg >> 3) + (blockIdx.x >> 3);
  const int tileM = (wg & 127) * 256;
  const int tileN = (wg >> 7) * 256;

  // ---- staging source pointers (pre-swizzled global addresses) ----
  // Half layout (16 KiB = 128 LDS rows x 128 B):
  //  A half h: LDS row rr <-> global M row (rr>>6)*128 + h*64 + (rr&63)
  //  B half h: LDS row rr <-> global N row (rr>>5)*64  + h*32 + (rr&31)
  const u16* sA[2][2]; const u16* sB[2][2];
  {
    const int off0 = wid*1024 + lane*16;
    #pragma unroll
    for (int r = 0; r < 2; ++r){
      const int off = r*8192 + off0;          // byte pos inside 16KB half
      const int rr  = off >> 7;               // 0..127
      const int g   = (((off >> 4) & 7) ^ (rr & 7)) * 8;   // swizzled k-chunk (elems)
      #pragma unroll
      for (int h = 0; h < 2; ++h){
        sA[h][r] = A  + (size_t)(tileM + (rr>>6)*128 + h*64 + (rr&63)) * KC + g;
        sB[h][r] = Bt + (size_t)(tileN + (rr>>5)*64  + h*32 + (rr&31)) * KC + g;
      }
    }
  }
  auto stA = [&](int h, int kt){
    char* d = smem + h*16384 + wid*1024;
    async16(sA[h][0] + kt, (u16*)d);
    async16(sA[h][1] + kt, (u16*)(d + 8192));
  };
  auto stB = [&](int h, int kt){
    char* d = smem + 32768 + h*16384 + wid*1024;
    async16(sB[h][0] + kt, (u16*)d);
    async16(sB[h][1] + kt, (u16*)(d + 8192));
  };

  // ---- fragment read offsets ----
  const int cO0  = ((quad)     ^ (lr & 7)) * 16;   // ks=0 swizzled chunk byte
  const int cO1  = ((quad ^ 4) ^ (lr & 7)) * 16;   // ks=1
  const int aRow = (wm*64 + lr) * 128;             // + mh*16384 + i*2048
  const int bRow = (wn*32 + lr) * 128;             // + 32768 + nh*16384 + j*2048

  bf16x8 ar[4][2], br0[2][2], br1[2][2];
  f32x4 acc[2][2][4][2] = {};   // [mh][nh][i][j]

  auto ldA = [&](int mh){
    #pragma unroll
    for (int i = 0; i < 4; ++i){
      ar[i][0] = *(const bf16x8*)(smem + mh*16384 + aRow + i*2048 + cO0);
      ar[i][1] = *(const bf16x8*)(smem + mh*16384 + aRow + i*2048 + cO1);
    }
  };
  auto ldB = [&](int nh, bf16x8 (&br)[2][2]){
    #pragma unroll
    for (int j = 0; j < 2; ++j){
      br[j][0] = *(const bf16x8*)(smem + 32768 + nh*16384 + bRow + j*2048 + cO0);
      br[j][1] = *(const bf16x8*)(smem + 32768 + nh*16384 + bRow + j*2048 + cO1);
    }
  };
  auto MF = [&](int mh, int nh, bf16x8 (&br)[2][2]){
    __builtin_amdgcn_s_setprio(1);
    #pragma unroll
    for (int i = 0; i < 4; ++i)
      #pragma unroll
      for (int j = 0; j < 2; ++j){
        acc[mh][nh][i][j] = __builtin_amdgcn_mfma_f32_16x16x32_bf16(br[j][0], ar[i][0], acc[mh][nh][i][j], 0, 0, 0);
        acc[mh][nh][i][j] = __builtin_amdgcn_mfma_f32_16x16x32_bf16(br[j][1], ar[i][1], acc[mh][nh][i][j], 0, 0, 0);
      }
    __builtin_amdgcn_s_setprio(0);
  };

  // ---- prologue: stage tile0 (A0,B0 oldest -> vmcnt(4) waits exactly those) ----
  stA(0, 0); stB(0, 0); stB(1, 0); stA(1, 0);
  VMCNT(4);
  BARRIER();

  // ---- main loop (tiles 0..NK-2), tail peeled ----
  #pragma unroll 1
  for (int t = 0; t < NK-1; ++t){
    const int kt = (t+1)*64;
    // q0
    ldA(0); ldB(0, br0);
    BARRIER(); LGKM0();
    MF(0, 0, br0);
    VMCNT(2);                       // B1(t) landed (staged q2(t-1))
    BARRIER();
    // q1
    ldB(1, br1);
    stA(0, kt); stB(0, kt);         // slots A0,B0 freed after q0
    BARRIER(); LGKM0();
    MF(0, 1, br1);
    VMCNT(4);                       // A1(t) landed (staged q3(t-1))
    BARRIER();
    // q2
    ldA(1);
    stB(1, kt);                     // slot B1 freed after q1
    BARRIER(); LGKM0();
    MF(1, 1, br1);
    BARRIER();
    // q3 (no LDS read: A1 in ar, B0 held in br0)
    stA(1, kt);                     // slot A1 freed after q2
    MF(1, 0, br0);
    VMCNT(4);                       // A0,B0(t+1) landed (staged q1(t))
    BARRIER();
  }
  // ---- tail tile (no staging; drain) ----
  ldA(0); ldB(0, br0);
  BARRIER(); LGKM0();
  MF(0, 0, br0);
  VMCNT(2);
  BARRIER();
  ldB(1, br1);
  BARRIER(); LGKM0();
  MF(0, 1, br1);
  VMCNT(0);                         // A1 of last tile (only 2 loads left)
  BARRIER();
  ldA(1);
  BARRIER(); LGKM0();
  MF(1, 1, br1);
  BARRIER();                        // all LDS reads done -> smem reusable below
  MF(1, 0, br0);

  // ---- epilogue ----
  // acc[mh][nh][i][j][r] = C[tileM + wm*128 + mh*64 + i*16 + lr]
  //                         [tileN + wn*64 + nh*32 + j*16 + quad*4 + r]
  if (EPI == 3){
    #pragma unroll
    for (int mh = 0; mh < 2; ++mh)
    #pragma unroll
    for (int i = 0; i < 4; ++i){
      const int row = tileM + wm*128 + mh*64 + i*16 + lr;
      #pragma unroll
      for (int nh = 0; nh < 2; ++nh)
      #pragma unroll
      for (int j = 0; j < 2; ++j){
        const int colb = tileN + wn*64 + nh*32 + j*16 + quad*4;
        const float4 bvv = *(const float4*)(bias0 + colb);
        float4 o;
        #pragma unroll
        for (int r = 0; r < 4; ++r)
          ((float*)&o)[r] = 2.0f * (acc[mh][nh][i][j][r] + ((const float*)&bvv)[r]);
        *(float4*)(outf + (size_t)row * 512 + colb) = o;
      }
    }
    return;
  }

  // bf16 epilogues with per-wave LDS bounce -> full 128-B-line global stores.
  char* eb = smem + wid * 2304;              // 16 rows x 144 B
  const int mat = (EPI == 0) ? (tileN >> 10) : 0;   // 0:Q 1:K 2:V
  const float* biasP = bias0;
  u16* outP = out0;
  int ldO = 1024, cb0 = tileN + wn*64;
  if (EPI == 0){
    biasP = (mat==0) ? bias0 : (mat==1) ? bias1 : bias2;
    outP  = (mat==0) ? out0  : (mat==1) ? out1  : out2;
    cb0   = (tileN & 1023) + wn*64;
  } else if (EPI == 1){
    ldO = 512;
  }

  #pragma unroll
  for (int mh = 0; mh < 2; ++mh)
  #pragma unroll
  for (int i = 0; i < 4; ++i){
    const int row = tileM + wm*128 + mh*64 + i*16 + lr;
    #pragma unroll
    for (int nh = 0; nh < 2; ++nh)
    #pragma unroll
    for (int j = 0; j < 2; ++j){
      const int cl = (nh*2 + j)*16 + quad*4;
      const float4 bvv = *(const float4*)(biasP + cb0 + cl);
      u16 o[4];
      if (EPI == 0){
        float4 wbv = {0,0,0,0};
        if (mat == 1) wbv = *(const float4*)(wbias + cb0 + cl);
        #pragma unroll
        for (int r = 0; r < 4; ++r){
          float v = acc[mh][nh][i][j][r] + ((const float*)&bvv)[r];
          if (mat == 0)      v = fast_rcp(1.0f + __expf(-v));
          else if (mat == 1) v = __expf(v + ((const float*)&wbv)[r]);
          o[r] = f2bf(v);
        }
      } else if (EPI == 1){
        uint2 pr = *(const uint2*)(resid + (size_t)row * 512 + cb0 + cl);
        const u16* rp = (const u16*)&pr;
        #pragma unroll
        for (int r = 0; r < 4; ++r)
          o[r] = f2bf(acc[mh][nh][i][j][r] + ((const float*)&bvv)[r] + bf2f(rp[r]));
      } else {
        #pragma unroll
        for (int r = 0; r < 4; ++r){
          float v  = acc[mh][nh][i][j][r] + ((const float*)&bvv)[r];
          float u2 = 2.0f * v * (0.7978845608f + 0.0356774081f * v * v);
          float tg = 1.0f - 2.0f * fast_rcp(1.0f + __expf(u2));
          o[r] = f2bf(0.5f * v * (1.0f + tg));
        }
      }
      *(uint2*)(eb + lr*144 + cl*2) = *(const uint2*)o;
    }
    __asm__ volatile("s_waitcnt lgkmcnt(0)" ::: "memory");
    uint4 p0 = *(const uint4*)(eb + lr*144 + quad*32);
    uint4 p1 = *(const uint4*)(eb + lr*144 + quad*32 + 16);
    __asm__ volatile("s_waitcnt lgkmcnt(0)" ::: "memory");
    u16* gp = outP + (size_t)row * ldO + cb0 + quad*16;
    *(uint4*)gp = p0;
    *(uint4*)(gp + 8) = p1;
  }
}

extern "C" void kernel_launch(void* const* d_in, const int* in_sizes, int n_in,
                              void* d_out, int out_size, void* d_ws, size_t ws_size,
                              hipStream_t stream) {
  const float* x     = (const float*)d_in[0];
  const float* gamma = (const float*)d_in[1];
  const float* beta  = (const float*)d_in[2];
  const float* Wq    = (const float*)d_in[3];
  const float* bq    = (const float*)d_in[4];
  const float* Wk    = (const float*)d_in[5];
  const float* bk    = (const float*)d_in[6];
  const float* Wv    = (const float*)d_in[7];
  const float* bv    = (const float*)d_in[8];
  const float* wbias = (const float*)d_in[9];
  const float* Wo    = (const float*)d_in[10];
  const float* bo    = (const float*)d_in[11];
  const float* W1    = (const float*)d_in[12];
  const float* b1    = (const float*)d_in[13];
  const float* W2    = (const float*)d_in[14];
  const float* b2    = (const float*)d_in[15];
  float* out = (float*)d_out;

  char* w = (char*)d_ws;
  const size_t MB = 1ull << 20;
  u16* WqkvT = (u16*)(w + 0*MB);      // [3072][512]  (WqT | WkT | WvT)
  u16* WoT   = (u16*)(w + 3*MB);      // [512][1024]
  u16* W1T   = (u16*)(w + 4*MB);      // [1024][512]
  u16* W2T   = (u16*)(w + 5*MB);      // [512][1024]
  u16* x1b   = (u16*)(w + 6*MB);      // [32768][512]
  u16* Qs    = (u16*)(w + 38*MB);     // [32768][1024]
  u16* Nu    = (u16*)(w + 102*MB);    // [32768][1024]
  u16* Vb    = (u16*)(w + 166*MB);    // [32768][1024]
  u16* Yt    = Nu;                    // in-place over numer
  u16* x2b   = Vb;                    // reuse (V consumed by aft_fused)
  u16* x3b   = (u16*)(w + 198*MB);
  u16* hb    = Qs;                    // reuse (Qsig consumed by aft_fused)

  transpose_all<<<dim3(32, 32, 6), dim3(32, 8), 0, stream>>>(
      Wq, Wk, Wv, Wo, W1, W2,
      WqkvT, WqkvT + 1024*512, WqkvT + 2*1024*512, WoT, W1T, W2T);

  ln_kernel<false><<<8192, 256, 0, stream>>>(x, gamma, beta, x1b);

  // QKV: [32768,512] @ [3072,512]^T ; 128 M-tiles x 12 N-tiles
  gemm256<0, 512><<<1536, 512, 0, stream>>>(x1b, WqkvT,
      bq, wbias, Qs, Nu, Vb, bk, bv, nullptr, nullptr);

  aft_fused<<<2048, 256, 0, stream>>>(Nu, Vb, Qs, Yt);

  // attn out: [32768,1024] @ [512,1024]^T ; 128 x 2
  gemm256<1, 1024><<<256, 512, 0, stream>>>(Yt, WoT,
      bo, nullptr, x2b, nullptr, nullptr, nullptr, nullptr, x1b, nullptr);

  ln_kernel<true><<<8192, 256, 0, stream>>>(x2b, gamma, beta, x3b);

  // mlp1: [32768,512] @ [1024,512]^T ; 128 x 4
  gemm256<2, 512><<<512, 512, 0, stream>>>(x3b, W1T,
      b1, nullptr, hb, nullptr, nullptr, nullptr, nullptr, nullptr, nullptr);

  // mlp2: [32768,1024] @ [512,1024]^T ; 128 x 2
  gemm256<3, 1024><<<256, 512, 0, stream>>>(hb, W2T,
      b2, nullptr, nullptr, nullptr, nullptr, nullptr, nullptr, nullptr, out);
}

// Round 3
// 455.928 us; speedup vs baseline: 1.0675x; 1.0615x over previous
//
#include <hip/hip_runtime.h>
#include <hip/hip_bf16.h>
#include <cstdint>

using u16 = unsigned short;
using u32 = unsigned int;

typedef __bf16 bf16x8 __attribute__((ext_vector_type(8)));
typedef float  f32x4  __attribute__((ext_vector_type(4)));

#define DEV static __device__ __forceinline__

DEV float bf2f(u16 u){ union { u32 u; float f; } c; c.u = ((u32)u) << 16; return c.f; }

// hardware RNE f32->bf16
DEV u16 f2bf(float f){
  __bf16 h = (__bf16)f;
  return __builtin_bit_cast(u16, h);
}

DEV float fast_rcp(float x){ return __builtin_amdgcn_rcpf(x); }

DEV void async16(const u16* g, u16* l){
  __builtin_amdgcn_global_load_lds((const __attribute__((address_space(1))) u32*)g,
                                   (__attribute__((address_space(3))) u32*)l,
                                   16, 0, 0);
}

#define BARRIER() __builtin_amdgcn_s_barrier()
#define LGKM0() do { __asm__ volatile("s_waitcnt lgkmcnt(0)" ::: "memory"); \
                     __builtin_amdgcn_sched_barrier(0); } while (0)
#define VMCNT(n) __asm__ volatile("s_waitcnt vmcnt(" #n ")" ::: "memory")

// ---------------- fused weight transposes + f32->bf16 (one launch) ----------------
__global__ __launch_bounds__(256)
void transpose_all(const float* __restrict__ W0, const float* __restrict__ W1,
                   const float* __restrict__ W2, const float* __restrict__ W3,
                   const float* __restrict__ W4, const float* __restrict__ W5,
                   u16* __restrict__ T0, u16* __restrict__ T1, u16* __restrict__ T2,
                   u16* __restrict__ T3, u16* __restrict__ T4, u16* __restrict__ T5){
  const int z = blockIdx.z;
  const float* W; u16* WT; int R, C;
  switch (z){
    case 0:  W = W0; WT = T0; R = 512;  C = 1024; break;
    case 1:  W = W1; WT = T1; R = 512;  C = 1024; break;
    case 2:  W = W2; WT = T2; R = 512;  C = 1024; break;
    case 3:  W = W3; WT = T3; R = 1024; C = 512;  break;
    case 4:  W = W4; WT = T4; R = 512;  C = 1024; break;
    default: W = W5; WT = T5; R = 1024; C = 512;  break;
  }
  const int c0 = blockIdx.x * 32, r0 = blockIdx.y * 32;
  if (c0 >= C || r0 >= R) return;
  __shared__ float tile[32][33];
  const int tx = threadIdx.x, ty = threadIdx.y;  // (32,8)
  #pragma unroll
  for (int j = 0; j < 4; ++j)
    tile[ty + j*8][tx] = W[(size_t)(r0 + ty + j*8) * C + (c0 + tx)];
  __syncthreads();
  #pragma unroll
  for (int j = 0; j < 4; ++j)
    WT[(size_t)(c0 + ty + j*8) * R + (r0 + tx)] = f2bf(tile[tx][ty + j*8]);
}

// ---------------- LayerNorm: one wave per 512-elem row ----------------
template<bool BF16IN>
__global__ __launch_bounds__(256)
void ln_kernel(const void* __restrict__ xin, const float* __restrict__ gamma,
               const float* __restrict__ beta, u16* __restrict__ xout){
  const int wid = threadIdx.x >> 6;
  const int lane = threadIdx.x & 63;
  const size_t row = (size_t)blockIdx.x * 4 + wid;
  const int d0 = lane * 8;
  float v[8];
  if constexpr (BF16IN){
    const u16* xp = (const u16*)xin + row * 512 + d0;
    uint4 p = *(const uint4*)xp;
    const u16* s = (const u16*)&p;
    #pragma unroll
    for (int i = 0; i < 8; ++i) v[i] = bf2f(s[i]);
  } else {
    const float* xp = (const float*)xin + row * 512 + d0;
    float4 p0 = *(const float4*)xp;
    float4 p1 = *(const float4*)(xp + 4);
    v[0]=p0.x; v[1]=p0.y; v[2]=p0.z; v[3]=p0.w;
    v[4]=p1.x; v[5]=p1.y; v[6]=p1.z; v[7]=p1.w;
  }
  float s = 0.f, sq = 0.f;
  #pragma unroll
  for (int i = 0; i < 8; ++i){ s += v[i]; sq += v[i]*v[i]; }
  #pragma unroll
  for (int o = 32; o >= 1; o >>= 1){ s += __shfl_xor(s, o); sq += __shfl_xor(sq, o); }
  const float mu  = s * (1.0f/512.0f);
  const float var = sq * (1.0f/512.0f) - mu*mu;
  const float rstd = rsqrtf(var + 1e-5f);
  const float4 g0 = *(const float4*)(gamma + d0);
  const float4 g1 = *(const float4*)(gamma + d0 + 4);
  const float4 b0 = *(const float4*)(beta + d0);
  const float4 b1 = *(const float4*)(beta + d0 + 4);
  float gg[8] = {g0.x,g0.y,g0.z,g0.w,g1.x,g1.y,g1.z,g1.w};
  float bb[8] = {b0.x,b0.y,b0.z,b0.w,b1.x,b1.y,b1.z,b1.w};
  u16 o8[8];
  #pragma unroll
  for (int i = 0; i < 8; ++i)
    o8[i] = f2bf((v[i]-mu)*rstd*gg[i] + bb[i]);
  *(uint4*)(xout + row*512 + d0) = *(const uint4*)o8;
}

// ---- fused AFT: weighted[t,h] = sum_b n*v / sum_b n ; Yt[b,t,h] = Qsig[b,t,h]*weighted ----
__global__ __launch_bounds__(256)
void aft_fused(const u16* __restrict__ numer, const u16* __restrict__ V,
               const u16* __restrict__ qs, u16* __restrict__ yt){
  const size_t TH = (size_t)4096 * 1024;
  const size_t i8 = ((size_t)blockIdx.x * 256 + threadIdx.x) * 8;
  float den[8], ws[8];
  #pragma unroll
  for (int j = 0; j < 8; ++j){ den[j] = 0.f; ws[j] = 0.f; }
  #pragma unroll
  for (int b = 0; b < 8; ++b){
    uint4 pn = *(const uint4*)(numer + b*TH + i8);
    uint4 pv = *(const uint4*)(V     + b*TH + i8);
    const u16* n = (const u16*)&pn;
    const u16* v = (const u16*)&pv;
    #pragma unroll
    for (int j = 0; j < 8; ++j){ float nf = bf2f(n[j]); den[j] += nf; ws[j] += nf * bf2f(v[j]); }
  }
  float w[8];
  #pragma unroll
  for (int j = 0; j < 8; ++j) w[j] = ws[j] * fast_rcp(den[j]);
  #pragma unroll
  for (int b = 0; b < 8; ++b){
    uint4 pq = *(const uint4*)(qs + b*TH + i8);
    const u16* q = (const u16*)&pq;
    u16 o[8];
    #pragma unroll
    for (int j = 0; j < 8; ++j) o[j] = f2bf(bf2f(q[j]) * w[j]);
    *(uint4*)(yt + b*TH + i8) = *(const uint4*)o;
  }
}

// ========= 256x256 bf16 MFMA GEMM, C = A[M,K] @ Bt[N,K]^T — 8-phase, 64KB static LDS =========
// 8 waves (2M x 4N), per-wave 128x64 output, BK=64, SINGLE 64 KiB buffer. Quadrant rotation
// with register-held B0/B1 so every LDS half is ds_read exactly once per tile and its slot
// is immediately re-staged for tile t+1:
//   q0: ds_read A0,B0 -> MF(0,0)                    | end: vmcnt(2)  (B1(t) landed)
//   q1: ds_read B1 ; stage (t+1).A0,B0 -> MF(0,1)   | end: vmcnt(4)  (A1(t) landed)
//   q2: ds_read A1 ; stage (t+1).B1   -> MF(1,1)    | end: barrier only
//   q3: stage (t+1).A1 ; MF(1,0) [regs only]        | end: vmcnt(4)  (A0,B0(t+1) landed)
// Counted vmcnt keeps 2-4 half-tiles in flight across barriers. lgkmcnt(0)+sched_barrier
// before each MFMA cluster; setprio(1) around MFMA. XOR swizzle (chunk ^= row&7) on
// pre-swizzled GLOBAL source + swizzled ds_read address; LDS writes stay linear.
//
// GRID MAPPING (round-3 fix): XCD-pinned supergroups of 4 M-tiles x all N-tiles, M fastest.
// A-chunk (4x256 rows x K = 1-2 MB) + B-sweep (nNT x 256 x K = 1-3 MB) stay resident in the
// 4 MB per-XCD L2, so staging loads are L2 hits (~200 cyc) — within the 2-phase vmcnt slack.
// Each XCD owns a disjoint A range (no cross-XCD replication).
template<int EPI, int KC>
__global__ __launch_bounds__(512, 2)
void gemm256(const u16* __restrict__ A, const u16* __restrict__ Bt,
             const float* __restrict__ bias0, const float* __restrict__ wbias,
             u16* __restrict__ out0, u16* __restrict__ out1, u16* __restrict__ out2,
             const float* __restrict__ bias1, const float* __restrict__ bias2,
             const u16* __restrict__ resid, float* __restrict__ outf){
  constexpr int NK = KC / 64;
  __shared__ __align__(16) char smem[65536];  // A0|A1|B0|B1, 16 KiB each

  const int tid  = threadIdx.x;
  const int wid  = tid >> 6;
  const int lane = tid & 63;
  const int quad = lane >> 4;
  const int lr   = lane & 15;
  const int wm   = wid & 1;      // M-wave (2)
  const int wn   = wid >> 1;     // N-wave (4)

  // bijective XCD swizzle + L2 supergroups (4 M-tiles x all N-tiles, M fastest)
  const int nwg = gridDim.x;                 // = 128 * nNT (always % 8 == 0)
  const int wg  = (blockIdx.x & 7) * (nwg >> 3) + (blockIdx.x >> 3);
  const int nNT = nwg >> 7;                  // N-tiles: 12 / 2 / 4 / 2
  const int sgs = nNT << 2;                  // supergroup size (4*nNT)
  const int sg  = wg / sgs;
  const int r   = wg - sg * sgs;
  const int tileM = (sg*4 + (r & 3)) * 256;
  const int tileN = (r >> 2) * 256;

  // ---- staging source pointers (pre-swizzled global addresses) ----
  // Half layout (16 KiB = 128 LDS rows x 128 B):
  //  A half h: LDS row rr <-> global M row (rr>>6)*128 + h*64 + (rr&63)
  //  B half h: LDS row rr <-> global N row (rr>>5)*64  + h*32 + (rr&31)
  const u16* sA[2][2]; const u16* sB[2][2];
  {
    const int off0 = wid*1024 + lane*16;
    #pragma unroll
    for (int rr_ = 0; rr_ < 2; ++rr_){
      const int off = rr_*8192 + off0;        // byte pos inside 16KB half
      const int rr  = off >> 7;               // 0..127
      const int g   = (((off >> 4) & 7) ^ (rr & 7)) * 8;   // swizzled k-chunk (elems)
      #pragma unroll
      for (int h = 0; h < 2; ++h){
        sA[h][rr_] = A  + (size_t)(tileM + (rr>>6)*128 + h*64 + (rr&63)) * KC + g;
        sB[h][rr_] = Bt + (size_t)(tileN + (rr>>5)*64  + h*32 + (rr&31)) * KC + g;
      }
    }
  }
  auto stA = [&](int h, int kt){
    char* d = smem + h*16384 + wid*1024;
    async16(sA[h][0] + kt, (u16*)d);
    async16(sA[h][1] + kt, (u16*)(d + 8192));
  };
  auto stB = [&](int h, int kt){
    char* d = smem + 32768 + h*16384 + wid*1024;
    async16(sB[h][0] + kt, (u16*)d);
    async16(sB[h][1] + kt, (u16*)(d + 8192));
  };

  // ---- fragment read offsets ----
  const int cO0  = ((quad)     ^ (lr & 7)) * 16;   // ks=0 swizzled chunk byte
  const int cO1  = ((quad ^ 4) ^ (lr & 7)) * 16;   // ks=1
  const int aRow = (wm*64 + lr) * 128;             // + mh*16384 + i*2048
  const int bRow = (wn*32 + lr) * 128;             // + 32768 + nh*16384 + j*2048

  bf16x8 ar[4][2], br0[2][2], br1[2][2];
  f32x4 acc[2][2][4][2] = {};   // [mh][nh][i][j]

  auto ldA = [&](int mh){
    #pragma unroll
    for (int i = 0; i < 4; ++i){
      ar[i][0] = *(const bf16x8*)(smem + mh*16384 + aRow + i*2048 + cO0);
      ar[i][1] = *(const bf16x8*)(smem + mh*16384 + aRow + i*2048 + cO1);
    }
  };
  auto ldB = [&](int nh, bf16x8 (&br)[2][2]){
    #pragma unroll
    for (int j = 0; j < 2; ++j){
      br[j][0] = *(const bf16x8*)(smem + 32768 + nh*16384 + bRow + j*2048 + cO0);
      br[j][1] = *(const bf16x8*)(smem + 32768 + nh*16384 + bRow + j*2048 + cO1);
    }
  };
  auto MF = [&](int mh, int nh, bf16x8 (&br)[2][2]){
    __builtin_amdgcn_s_setprio(1);
    #pragma unroll
    for (int i = 0; i < 4; ++i)
      #pragma unroll
      for (int j = 0; j < 2; ++j){
        acc[mh][nh][i][j] = __builtin_amdgcn_mfma_f32_16x16x32_bf16(br[j][0], ar[i][0], acc[mh][nh][i][j], 0, 0, 0);
        acc[mh][nh][i][j] = __builtin_amdgcn_mfma_f32_16x16x32_bf16(br[j][1], ar[i][1], acc[mh][nh][i][j], 0, 0, 0);
      }
    __builtin_amdgcn_s_setprio(0);
  };

  // ---- prologue: stage tile0 (A0,B0 oldest -> vmcnt(4) waits exactly those) ----
  stA(0, 0); stB(0, 0); stB(1, 0); stA(1, 0);
  VMCNT(4);
  BARRIER();

  // ---- main loop (tiles 0..NK-2), tail peeled ----
  #pragma unroll 1
  for (int t = 0; t < NK-1; ++t){
    const int kt = (t+1)*64;
    // q0
    ldA(0); ldB(0, br0);
    BARRIER(); LGKM0();
    MF(0, 0, br0);
    VMCNT(2);                       // B1(t) landed (staged q2(t-1))
    BARRIER();
    // q1
    ldB(1, br1);
    stA(0, kt); stB(0, kt);         // slots A0,B0 freed after q0
    BARRIER(); LGKM0();
    MF(0, 1, br1);
    VMCNT(4);                       // A1(t) landed (staged q3(t-1))
    BARRIER();
    // q2
    ldA(1);
    stB(1, kt);                     // slot B1 freed after q1
    BARRIER(); LGKM0();
    MF(1, 1, br1);
    BARRIER();
    // q3 (no LDS read: A1 in ar, B0 held in br0)
    stA(1, kt);                     // slot A1 freed after q2
    MF(1, 0, br0);
    VMCNT(4);                       // A0,B0(t+1) landed (staged q1(t))
    BARRIER();
  }
  // ---- tail tile (no staging; drain) ----
  ldA(0); ldB(0, br0);
  BARRIER(); LGKM0();
  MF(0, 0, br0);
  VMCNT(2);
  BARRIER();
  ldB(1, br1);
  BARRIER(); LGKM0();
  MF(0, 1, br1);
  VMCNT(0);                         // A1 of last tile (only 2 loads left)
  BARRIER();
  ldA(1);
  BARRIER(); LGKM0();
  MF(1, 1, br1);
  BARRIER();                        // all LDS reads done -> smem reusable below
  MF(1, 0, br0);

  // ---- epilogue ----
  // acc[mh][nh][i][j][r] = C[tileM + wm*128 + mh*64 + i*16 + lr]
  //                         [tileN + wn*64 + nh*32 + j*16 + quad*4 + r]
  if (EPI == 3){
    #pragma unroll
    for (int mh = 0; mh < 2; ++mh)
    #pragma unroll
    for (int i = 0; i < 4; ++i){
      const int row = tileM + wm*128 + mh*64 + i*16 + lr;
      #pragma unroll
      for (int nh = 0; nh < 2; ++nh)
      #pragma unroll
      for (int j = 0; j < 2; ++j){
        const int colb = tileN + wn*64 + nh*32 + j*16 + quad*4;
        const float4 bvv = *(const float4*)(bias0 + colb);
        float4 o;
        #pragma unroll
        for (int r_ = 0; r_ < 4; ++r_)
          ((float*)&o)[r_] = 2.0f * (acc[mh][nh][i][j][r_] + ((const float*)&bvv)[r_]);
        *(float4*)(outf + (size_t)row * 512 + colb) = o;
      }
    }
    return;
  }

  // bf16 epilogues with per-wave LDS bounce -> full 128-B-line global stores.
  char* eb = smem + wid * 2304;              // 16 rows x 144 B
  const int mat = (EPI == 0) ? (tileN >> 10) : 0;   // 0:Q 1:K 2:V
  const float* biasP = bias0;
  u16* outP = out0;
  int ldO = 1024, cb0 = tileN + wn*64;
  if (EPI == 0){
    biasP = (mat==0) ? bias0 : (mat==1) ? bias1 : bias2;
    outP  = (mat==0) ? out0  : (mat==1) ? out1  : out2;
    cb0   = (tileN & 1023) + wn*64;
  } else if (EPI == 1){
    ldO = 512;
  }

  #pragma unroll
  for (int mh = 0; mh < 2; ++mh)
  #pragma unroll
  for (int i = 0; i < 4; ++i){
    const int row = tileM + wm*128 + mh*64 + i*16 + lr;
    #pragma unroll
    for (int nh = 0; nh < 2; ++nh)
    #pragma unroll
    for (int j = 0; j < 2; ++j){
      const int cl = (nh*2 + j)*16 + quad*4;
      const float4 bvv = *(const float4*)(biasP + cb0 + cl);
      u16 o[4];
      if (EPI == 0){
        float4 wbv = {0,0,0,0};
        if (mat == 1) wbv = *(const float4*)(wbias + cb0 + cl);
        #pragma unroll
        for (int r_ = 0; r_ < 4; ++r_){
          float v = acc[mh][nh][i][j][r_] + ((const float*)&bvv)[r_];
          if (mat == 0)      v = fast_rcp(1.0f + __expf(-v));
          else if (mat == 1) v = __expf(v + ((const float*)&wbv)[r_]);
          o[r_] = f2bf(v);
        }
      } else if (EPI == 1){
        uint2 pr = *(const uint2*)(resid + (size_t)row * 512 + cb0 + cl);
        const u16* rp = (const u16*)&pr;
        #pragma unroll
        for (int r_ = 0; r_ < 4; ++r_)
          o[r_] = f2bf(acc[mh][nh][i][j][r_] + ((const float*)&bvv)[r_] + bf2f(rp[r_]));
      } else {
        #pragma unroll
        for (int r_ = 0; r_ < 4; ++r_){
          float v  = acc[mh][nh][i][j][r_] + ((const float*)&bvv)[r_];
          float u2 = 2.0f * v * (0.7978845608f + 0.0356774081f * v * v);
          float tg = 1.0f - 2.0f * fast_rcp(1.0f + __expf(u2));
          o[r_] = f2bf(0.5f * v * (1.0f + tg));
        }
      }
      *(uint2*)(eb + lr*144 + cl*2) = *(const uint2*)o;
    }
    __asm__ volatile("s_waitcnt lgkmcnt(0)" ::: "memory");
    uint4 p0 = *(const uint4*)(eb + lr*144 + quad*32);
    uint4 p1 = *(const uint4*)(eb + lr*144 + quad*32 + 16);
    __asm__ volatile("s_waitcnt lgkmcnt(0)" ::: "memory");
    u16* gp = outP + (size_t)row * ldO + cb0 + quad*16;
    *(uint4*)gp = p0;
    *(uint4*)(gp + 8) = p1;
  }
}

extern "C" void kernel_launch(void* const* d_in, const int* in_sizes, int n_in,
                              void* d_out, int out_size, void* d_ws, size_t ws_size,
                              hipStream_t stream) {
  const float* x     = (const float*)d_in[0];
  const float* gamma = (const float*)d_in[1];
  const float* beta  = (const float*)d_in[2];
  const float* Wq    = (const float*)d_in[3];
  const float* bq    = (const float*)d_in[4];
  const float* Wk    = (const float*)d_in[5];
  const float* bk    = (const float*)d_in[6];
  const float* Wv    = (const float*)d_in[7];
  const float* bv    = (const float*)d_in[8];
  const float* wbias = (const float*)d_in[9];
  const float* Wo    = (const float*)d_in[10];
  const float* bo    = (const float*)d_in[11];
  const float* W1    = (const float*)d_in[12];
  const float* b1    = (const float*)d_in[13];
  const float* W2    = (const float*)d_in[14];
  const float* b2    = (const float*)d_in[15];
  float* out = (float*)d_out;

  char* w = (char*)d_ws;
  const size_t MB = 1ull << 20;
  u16* WqkvT = (u16*)(w + 0*MB);      // [3072][512]  (WqT | WkT | WvT)
  u16* WoT   = (u16*)(w + 3*MB);      // [512][1024]
  u16* W1T   = (u16*)(w + 4*MB);      // [1024][512]
  u16* W2T   = (u16*)(w + 5*MB);      // [512][1024]
  u16* x1b   = (u16*)(w + 6*MB);      // [32768][512]
  u16* Qs    = (u16*)(w + 38*MB);     // [32768][1024]
  u16* Nu    = (u16*)(w + 102*MB);    // [32768][1024]
  u16* Vb    = (u16*)(w + 166*MB);    // [32768][1024]
  u16* Yt    = Nu;                    // in-place over numer
  u16* x2b   = Vb;                    // reuse (V consumed by aft_fused)
  u16* x3b   = (u16*)(w + 198*MB);
  u16* hb    = Qs;                    // reuse (Qsig consumed by aft_fused)

  transpose_all<<<dim3(32, 32, 6), dim3(32, 8), 0, stream>>>(
      Wq, Wk, Wv, Wo, W1, W2,
      WqkvT, WqkvT + 1024*512, WqkvT + 2*1024*512, WoT, W1T, W2T);

  ln_kernel<false><<<8192, 256, 0, stream>>>(x, gamma, beta, x1b);

  // QKV: [32768,512] @ [3072,512]^T ; 128 M-tiles x 12 N-tiles
  gemm256<0, 512><<<1536, 512, 0, stream>>>(x1b, WqkvT,
      bq, wbias, Qs, Nu, Vb, bk, bv, nullptr, nullptr);

  aft_fused<<<2048, 256, 0, stream>>>(Nu, Vb, Qs, Yt);

  // attn out: [32768,1024] @ [512,1024]^T ; 128 x 2
  gemm256<1, 1024><<<256, 512, 0, stream>>>(Yt, WoT,
      bo, nullptr, x2b, nullptr, nullptr, nullptr, nullptr, x1b, nullptr);

  ln_kernel<true><<<8192, 256, 0, stream>>>(x2b, gamma, beta, x3b);

  // mlp1: [32768,512] @ [1024,512]^T ; 128 x 4
  gemm256<2, 512><<<512, 512, 0, stream>>>(x3b, W1T,
      b1, nullptr, hb, nullptr, nullptr, nullptr, nullptr, nullptr, nullptr);

  // mlp2: [32768,1024] @ [512,1024]^T ; 128 x 2
  gemm256<3, 1024><<<256, 512, 0, stream>>>(hb, W2T,
      b2, nullptr, nullptr, nullptr, nullptr, nullptr, nullptr, nullptr, out);
}